// Round 1
// baseline (500.616 us; speedup 1.0000x reference)
//
#include <hip/hip_runtime.h>
#include <hip/hip_bf16.h>
#include <math.h>

#define BINS 100
#define NBINS2 (BINS * BINS)

// ws layout (as unsigned words):
//   ws[0]           : monotone-encoded min of distances
//   ws[1]           : monotone-encoded max of distances
//   ws[16..16+9999] : joint histogram counts (uint)

static __device__ __forceinline__ unsigned enc_f32(float f) {
    unsigned u = __float_as_uint(f);
    return (u & 0x80000000u) ? ~u : (u | 0x80000000u);
}
static __device__ __forceinline__ float dec_f32(unsigned e) {
    unsigned u = (e & 0x80000000u) ? (e & 0x7FFFFFFFu) : ~e;
    return __uint_as_float(u);
}

__global__ void k_init(unsigned* ws) {
    int i = blockIdx.x * blockDim.x + threadIdx.x;
    if (i == 0) { ws[0] = 0xFFFFFFFFu; ws[1] = 0u; }
    if (i < NBINS2) ws[16 + i] = 0u;
}

__global__ __launch_bounds__(256) void k_minmax(const float* __restrict__ d, int n, unsigned* ws) {
    int tid = blockIdx.x * blockDim.x + threadIdx.x;
    int stride = gridDim.x * blockDim.x;
    float mn = INFINITY, mx = -INFINITY;
    int n4 = n >> 2;
    for (int i = tid; i < n4; i += stride) {
        float4 v = ((const float4*)d)[i];
        mn = fminf(mn, fminf(fminf(v.x, v.y), fminf(v.z, v.w)));
        mx = fmaxf(mx, fmaxf(fmaxf(v.x, v.y), fmaxf(v.z, v.w)));
    }
    int rem = n & 3;
    if (tid < rem) {
        float v = d[(n4 << 2) + tid];
        mn = fminf(mn, v);
        mx = fmaxf(mx, v);
    }
    #pragma unroll
    for (int off = 32; off; off >>= 1) {
        mn = fminf(mn, __shfl_xor(mn, off));
        mx = fmaxf(mx, __shfl_xor(mx, off));
    }
    if ((threadIdx.x & 63) == 0) {
        atomicMin(&ws[0], enc_f32(mn));
        atomicMax(&ws[1], enc_f32(mx));
    }
}

// One wave handles 2 rows per iteration: lanes 0-31 -> row 2*rp, lanes 32-63 -> row 2*rp+1.
// Each lane loads one float4 from each embedding (wave reads 1 KB coalesced per matrix).
__global__ __launch_bounds__(256) void k_simhist(
    const float* __restrict__ e1, const float* __restrict__ e2,
    const float* __restrict__ dist, int B, unsigned* ws)
{
    __shared__ unsigned s_hist[NBINS2];
    __shared__ double s_sedge[BINS + 1];
    __shared__ double s_dedge[BINS + 1];

    for (int i = threadIdx.x; i < NBINS2; i += blockDim.x) s_hist[i] = 0u;
    if (threadIdx.x <= BINS) {
        int i = threadIdx.x;
        // np.linspace(-1, 1, 101): edge[i] = i*delta + start; edge[last] = stop exactly
        double se = (double)i * 0.02 - 1.0;
        if (i == BINS) se = 1.0;
        s_sedge[i] = se;
        double dmn = (double)dec_f32(ws[0]);
        double dmx = (double)dec_f32(ws[1]);
        double delta = (dmx - dmn) / (double)BINS;
        double de = (double)i * delta + dmn;
        if (i == BINS) de = dmx;
        s_dedge[i] = de;
    }
    __syncthreads();

    const int lane = threadIdx.x & 63;
    const int wid = (blockIdx.x * blockDim.x + threadIdx.x) >> 6;
    const int nwaves = (gridDim.x * blockDim.x) >> 6;
    const int npairs = B >> 1;

    for (int rp = wid; rp < npairs; rp += nwaves) {
        size_t base = (size_t)rp * 256 + (size_t)(lane << 2);
        float4 a = *(const float4*)(e1 + base);
        float4 b = *(const float4*)(e2 + base);
        float dot = a.x * b.x + a.y * b.y + a.z * b.z + a.w * b.w;
        float n1  = a.x * a.x + a.y * a.y + a.z * a.z + a.w * a.w;
        float n2  = b.x * b.x + b.y * b.y + b.z * b.z + b.w * b.w;
        #pragma unroll
        for (int off = 16; off; off >>= 1) {
            dot += __shfl_xor(dot, off);
            n1  += __shfl_xor(n1, off);
            n2  += __shfl_xor(n2, off);
        }
        if ((lane & 31) == 0) {
            int row = (rp << 1) + (lane >> 5);
            float s = dot / (fmaxf(sqrtf(n1), 1e-12f) * fmaxf(sqrtf(n2), 1e-12f));
            float dv = dist[row];
            // searchsorted(side='right') - 1 via upper_bound over 101 edges
            double xs = (double)s;
            int lo = 0, hi = BINS + 1;
            while (lo < hi) { int mid = (lo + hi) >> 1; if (xs < s_sedge[mid]) hi = mid; else lo = mid + 1; }
            int is = lo - 1;
            double xd = (double)dv;
            lo = 0; hi = BINS + 1;
            while (lo < hi) { int mid = (lo + hi) >> 1; if (xd < s_dedge[mid]) hi = mid; else lo = mid + 1; }
            int id = lo - 1;
            if (is >= 0 && is < BINS && id >= 0 && id < BINS)
                atomicAdd(&s_hist[is * BINS + id], 1u);
        }
    }
    __syncthreads();
    unsigned* g = ws + 16;
    for (int i = threadIdx.x; i < NBINS2; i += blockDim.x) {
        unsigned c = s_hist[i];
        if (c) atomicAdd(&g[i], c);
    }
}

__global__ __launch_bounds__(256) void k_mi(const unsigned* __restrict__ counts, float* __restrict__ out) {
    __shared__ double s_lr[BINS], s_lc[BINS];
    __shared__ double s_red[256];
    const int tid = threadIdx.x;

    double t = 0.0;
    for (int i = tid; i < NBINS2; i += 256) t += (double)counts[i];
    s_red[tid] = t;
    __syncthreads();
    for (int off = 128; off; off >>= 1) {
        if (tid < off) s_red[tid] += s_red[tid + off];
        __syncthreads();
    }
    double tot = s_red[0];
    __syncthreads();

    if (tid < BINS) {
        double r = 0.0, c = 0.0;
        for (int j = 0; j < BINS; j++) {
            r += (double)counts[tid * BINS + j];
            c += (double)counts[j * BINS + tid];
        }
        s_lr[tid] = log(r / tot + 1e-10);
        s_lc[tid] = log(c / tot + 1e-10);
    }
    __syncthreads();

    double acc = 0.0;
    for (int k = tid; k < NBINS2; k += 256) {
        unsigned c = counts[k];
        if (c) {
            double p = (double)c / tot;
            acc += p * (log(p + 1e-10) - s_lr[k / BINS] - s_lc[k % BINS]);
        }
    }
    s_red[tid] = acc;
    __syncthreads();
    for (int off = 128; off; off >>= 1) {
        if (tid < off) s_red[tid] += s_red[tid + off];
        __syncthreads();
    }
    if (tid == 0) {
        double mi = s_red[0];
        double d1 = 0.0, d2 = 0.0;
        for (int i = 0; i < BINS; i++) { d1 -= s_lr[i]; d2 -= s_lc[i]; }
        out[0] = (float)(mi / fmin(d1, d2));
    }
}

extern "C" void kernel_launch(void* const* d_in, const int* in_sizes, int n_in,
                              void* d_out, int out_size, void* d_ws, size_t ws_size,
                              hipStream_t stream) {
    const float* e1 = (const float*)d_in[0];
    const float* e2 = (const float*)d_in[1];
    const float* dist = (const float*)d_in[2];
    const int B = in_sizes[2];
    unsigned* ws = (unsigned*)d_ws;

    k_init<<<(NBINS2 + 255) / 256, 256, 0, stream>>>(ws);
    k_minmax<<<1024, 256, 0, stream>>>(dist, B, ws);
    k_simhist<<<2048, 256, 0, stream>>>(e1, e2, dist, B, ws);
    k_mi<<<1, 256, 0, stream>>>(ws + 16, (float*)d_out);
}

// Round 2
// 311.349 us; speedup vs baseline: 1.6079x; 1.6079x over previous
//
#include <hip/hip_runtime.h>
#include <hip/hip_bf16.h>
#include <math.h>

#define BINS 100
#define NBINS2 (BINS * BINS)

// ws layout (unsigned words):
//   ws[0] : monotone-encoded min of distances
//   ws[1] : monotone-encoded max of distances
//   ws[16..16+9999] : joint histogram counts (uint)

static __device__ __forceinline__ unsigned enc_f32(float f) {
    unsigned u = __float_as_uint(f);
    return (u & 0x80000000u) ? ~u : (u | 0x80000000u);
}
static __device__ __forceinline__ float dec_f32(unsigned e) {
    unsigned u = (e & 0x80000000u) ? (e & 0x7FFFFFFFu) : ~e;
    return __uint_as_float(u);
}

__global__ void k_init(unsigned* ws) {
    int i = blockIdx.x * blockDim.x + threadIdx.x;
    if (i == 0) { ws[0] = 0xFFFFFFFFu; ws[1] = 0u; }
    if (i < NBINS2) ws[16 + i] = 0u;
}

__global__ __launch_bounds__(256) void k_minmax(const float* __restrict__ d, int n, unsigned* ws) {
    int tid = blockIdx.x * blockDim.x + threadIdx.x;
    int stride = gridDim.x * blockDim.x;
    float mn = INFINITY, mx = -INFINITY;
    int n4 = n >> 2;
    for (int i = tid; i < n4; i += stride) {
        float4 v = ((const float4*)d)[i];
        mn = fminf(mn, fminf(fminf(v.x, v.y), fminf(v.z, v.w)));
        mx = fmaxf(mx, fmaxf(fmaxf(v.x, v.y), fmaxf(v.z, v.w)));
    }
    int rem = n & 3;
    if (tid < rem) {
        float v = d[(n4 << 2) + tid];
        mn = fminf(mn, v);
        mx = fmaxf(mx, v);
    }
    #pragma unroll
    for (int off = 32; off; off >>= 1) {
        mn = fminf(mn, __shfl_xor(mn, off));
        mx = fmaxf(mx, __shfl_xor(mx, off));
    }
    if ((threadIdx.x & 63) == 0) {
        atomicMin(&ws[0], enc_f32(mn));
        atomicMax(&ws[1], enc_f32(mx));
    }
}

// searchsorted(edges, x, 'right') - 1: largest i with e[i] <= x < e[i+1].
// Arithmetic guess + fixup (edges near-uniform so fixup is <=1 step).
static __device__ __forceinline__ int bin_fix(double x, const double* __restrict__ e, int guess) {
    int i = guess;
    if (i < 0) i = 0; else if (i > BINS - 1) i = BINS - 1;
    while (i >= 0 && x < e[i]) --i;           // -> -1 if x < e[0]
    while (i < BINS && x >= e[i + 1]) ++i;    // -> BINS if x >= e[BINS]
    return i;
}

// 8 rows per wave-iteration: lane = 8*r + s; lane covers row (group*8+r),
// columns 4*(s+8k), k=0..3. Wave loads 8 KB per iteration, fully coalesced
// (8 contiguous 128B segments per load instruction).
__global__ __launch_bounds__(256) void k_simhist(
    const float* __restrict__ e1f, const float* __restrict__ e2f,
    const float* __restrict__ dist, int B, unsigned* ws)
{
    __shared__ unsigned s_hist[NBINS2];
    __shared__ double s_se[BINS + 1];
    __shared__ double s_de[BINS + 1];
    __shared__ double s_par[2];   // dist lo, dist inv_delta

    for (int i = threadIdx.x; i < NBINS2; i += 256) s_hist[i] = 0u;
    if (threadIdx.x <= BINS) {
        int i = threadIdx.x;
        s_se[i] = (i == BINS) ? 1.0 : ((double)i * 0.02 - 1.0);
        double dmn = (double)dec_f32(ws[0]);
        double dmx = (double)dec_f32(ws[1]);
        double delta = (dmx - dmn) * 0.01;
        s_de[i] = (i == BINS) ? dmx : ((double)i * delta + dmn);
        if (i == 0) {
            s_par[0] = dmn;
            s_par[1] = (delta > 0.0) ? (1.0 / delta) : 0.0;
        }
    }
    __syncthreads();

    const float4* __restrict__ e1 = (const float4*)e1f;
    const float4* __restrict__ e2 = (const float4*)e2f;
    const int lane = threadIdx.x & 63;
    const int r = lane >> 3, s = lane & 7;
    const int wid = (blockIdx.x * 256 + threadIdx.x) >> 6;
    const int nw = (gridDim.x * 256) >> 6;
    const int ngroups = B >> 3;
    const double dlo = s_par[0], dinv = s_par[1];

    for (int g = wid; g < ngroups; g += nw) {
        size_t base = (size_t)g * 256 + (size_t)(r * 32 + s);
        float4 a0 = e1[base], a1 = e1[base + 8], a2 = e1[base + 16], a3 = e1[base + 24];
        float4 b0 = e2[base], b1 = e2[base + 8], b2 = e2[base + 16], b3 = e2[base + 24];

        float dot = a0.x*b0.x + a0.y*b0.y + a0.z*b0.z + a0.w*b0.w
                  + a1.x*b1.x + a1.y*b1.y + a1.z*b1.z + a1.w*b1.w
                  + a2.x*b2.x + a2.y*b2.y + a2.z*b2.z + a2.w*b2.w
                  + a3.x*b3.x + a3.y*b3.y + a3.z*b3.z + a3.w*b3.w;
        float n1  = a0.x*a0.x + a0.y*a0.y + a0.z*a0.z + a0.w*a0.w
                  + a1.x*a1.x + a1.y*a1.y + a1.z*a1.z + a1.w*a1.w
                  + a2.x*a2.x + a2.y*a2.y + a2.z*a2.z + a2.w*a2.w
                  + a3.x*a3.x + a3.y*a3.y + a3.z*a3.z + a3.w*a3.w;
        float n2  = b0.x*b0.x + b0.y*b0.y + b0.z*b0.z + b0.w*b0.w
                  + b1.x*b1.x + b1.y*b1.y + b1.z*b1.z + b1.w*b1.w
                  + b2.x*b2.x + b2.y*b2.y + b2.z*b2.z + b2.w*b2.w
                  + b3.x*b3.x + b3.y*b3.y + b3.z*b3.z + b3.w*b3.w;

        dot += __shfl_xor(dot, 1); n1 += __shfl_xor(n1, 1); n2 += __shfl_xor(n2, 1);
        dot += __shfl_xor(dot, 2); n1 += __shfl_xor(n1, 2); n2 += __shfl_xor(n2, 2);
        dot += __shfl_xor(dot, 4); n1 += __shfl_xor(n1, 4); n2 += __shfl_xor(n2, 4);

        if (s == 0) {
            int row = (g << 3) + r;
            float sim = dot / (fmaxf(sqrtf(n1), 1e-12f) * fmaxf(sqrtf(n2), 1e-12f));
            double xs = (double)sim;
            int is = bin_fix(xs, s_se, (int)floor((xs + 1.0) * 50.0));
            double xd = (double)dist[row];
            int id = bin_fix(xd, s_de, (int)floor((xd - dlo) * dinv));
            if (is >= 0 && is < BINS && id >= 0 && id < BINS)
                atomicAdd(&s_hist[is * BINS + id], 1u);
        }
    }

    // tail rows (B % 8 != 0): wave 0 of block 0, one row at a time, 64 lanes coop
    int tail = B & 7;
    if (tail && blockIdx.x == 0 && threadIdx.x < 64) {
        for (int row = B - tail; row < B; ++row) {
            const float* p1 = e1f + (size_t)row * 128;
            const float* p2 = e2f + (size_t)row * 128;
            float a0 = p1[lane * 2], a1 = p1[lane * 2 + 1];
            float b0 = p2[lane * 2], b1 = p2[lane * 2 + 1];
            float dot = a0 * b0 + a1 * b1;
            float n1 = a0 * a0 + a1 * a1;
            float n2 = b0 * b0 + b1 * b1;
            #pragma unroll
            for (int off = 32; off; off >>= 1) {
                dot += __shfl_xor(dot, off);
                n1 += __shfl_xor(n1, off);
                n2 += __shfl_xor(n2, off);
            }
            if (lane == 0) {
                float sim = dot / (fmaxf(sqrtf(n1), 1e-12f) * fmaxf(sqrtf(n2), 1e-12f));
                double xs = (double)sim;
                int is = bin_fix(xs, s_se, (int)floor((xs + 1.0) * 50.0));
                double xd = (double)dist[row];
                int id = bin_fix(xd, s_de, (int)floor((xd - dlo) * dinv));
                if (is >= 0 && is < BINS && id >= 0 && id < BINS)
                    atomicAdd(&s_hist[is * BINS + id], 1u);
            }
        }
    }

    __syncthreads();
    unsigned* g = ws + 16;
    for (int i = threadIdx.x; i < NBINS2; i += 256) {
        unsigned c = s_hist[i];
        if (c) atomicAdd(&g[i], c);
    }
}

__global__ __launch_bounds__(1024) void k_mi(const unsigned* __restrict__ counts, float* __restrict__ out) {
    __shared__ unsigned s_c[NBINS2];
    __shared__ double s_red[1024];
    __shared__ double s_lr[BINS], s_lc[BINS];
    const int tid = threadIdx.x;

    double t = 0.0;
    for (int i = tid; i < NBINS2; i += 1024) {
        unsigned c = counts[i];
        s_c[i] = c;
        t += (double)c;
    }
    s_red[tid] = t;
    __syncthreads();
    for (int off = 512; off; off >>= 1) {
        if (tid < off) s_red[tid] += s_red[tid + off];
        __syncthreads();
    }
    double tot = s_red[0];
    __syncthreads();

    // row/col marginals: 8 threads per bin-row, shuffle-reduced
    if (tid < 8 * BINS) {
        int r = tid >> 3, s = tid & 7;
        double rs = 0.0, cs = 0.0;
        for (int j = s; j < BINS; j += 8) {
            rs += (double)s_c[r * BINS + j];
            cs += (double)s_c[j * BINS + r];
        }
        rs += __shfl_xor(rs, 1); cs += __shfl_xor(cs, 1);
        rs += __shfl_xor(rs, 2); cs += __shfl_xor(cs, 2);
        rs += __shfl_xor(rs, 4); cs += __shfl_xor(cs, 4);
        if (s == 0) {
            s_lr[r] = log(rs / tot + 1e-10);
            s_lc[r] = log(cs / tot + 1e-10);
        }
    }
    __syncthreads();

    double acc = 0.0;
    for (int i = tid; i < NBINS2; i += 1024) {
        unsigned c = s_c[i];
        if (c) {
            double p = (double)c / tot;
            acc += p * (log(p + 1e-10) - s_lr[i / BINS] - s_lc[i % BINS]);
        }
    }
    s_red[tid] = acc;
    __syncthreads();
    for (int off = 512; off; off >>= 1) {
        if (tid < off) s_red[tid] += s_red[tid + off];
        __syncthreads();
    }
    if (tid == 0) {
        double mi = s_red[0];
        double d1 = 0.0, d2 = 0.0;
        for (int i = 0; i < BINS; i++) { d1 -= s_lr[i]; d2 -= s_lc[i]; }
        out[0] = (float)(mi / fmin(d1, d2));
    }
}

extern "C" void kernel_launch(void* const* d_in, const int* in_sizes, int n_in,
                              void* d_out, int out_size, void* d_ws, size_t ws_size,
                              hipStream_t stream) {
    const float* e1 = (const float*)d_in[0];
    const float* e2 = (const float*)d_in[1];
    const float* dist = (const float*)d_in[2];
    const int B = in_sizes[2];
    unsigned* ws = (unsigned*)d_ws;

    k_init<<<(NBINS2 + 255) / 256, 256, 0, stream>>>(ws);
    k_minmax<<<1024, 256, 0, stream>>>(dist, B, ws);
    k_simhist<<<2048, 256, 0, stream>>>(e1, e2, dist, B, ws);
    k_mi<<<1, 1024, 0, stream>>>(ws + 16, (float*)d_out);
}